// Round 1
// baseline (1385.801 us; speedup 1.0000x reference)
//
#include <hip/hip_runtime.h>

#define SEQ 6
#define DIM 32
#define NH 4
#define NL 2
#define VOC 15
#define HID 128
#define EPB 32
#define ROWS (EPB*SEQ)          // 192 threads/block, one per (elem,seq) row
#define XNP 17                  // sXn row stride in u32 (34 bf16, even => aligned pairs)
#define KVP 18                  // sK/sV row stride in u32 (36 bf16, 8B-aligned uint2 reads)
#define VOFF (ROWS*KVP)
#define SHP 33                  // sH row stride in u32 (bank-spread for own-row r/w)

// ---- bf16 pack/unpack via bit ops (no API-name risk) ----
__device__ __forceinline__ unsigned int pack2(float a, float b) {
    unsigned int ua = __float_as_uint(a);
    unsigned int ub = __float_as_uint(b);
    ua += 0x7fffu + ((ua >> 16) & 1u);   // RNE to bf16
    ub += 0x7fffu + ((ub >> 16) & 1u);
    return (ua >> 16) | (ub & 0xffff0000u);
}
__device__ __forceinline__ float bf_lo(unsigned int u) { return __uint_as_float(u << 16); }
__device__ __forceinline__ float bf_hi(unsigned int u) { return __uint_as_float(u & 0xffff0000u); }

// out[c] (+)= sum_d x[d] * w[d*ldw + c]; x = bf16 pairs in LDS (own row), w = f32 LDS (broadcast)
template<int NC, bool ACC>
__device__ __forceinline__ void gemm_row(const unsigned int* __restrict__ xp, int kPairs,
                                         const float* __restrict__ w, int ldw,
                                         float* __restrict__ acc) {
    if (!ACC) {
        #pragma unroll
        for (int c = 0; c < NC; ++c) acc[c] = 0.0f;
    }
    #pragma unroll 1
    for (int dp = 0; dp < kPairs; ++dp) {
        unsigned int u = xp[dp];
        float x0 = bf_lo(u), x1 = bf_hi(u);
        const float* w0 = w + (2*dp)*ldw;
        const float* w1 = w0 + ldw;
        #pragma unroll
        for (int j = 0; j < NC/4; ++j) {
            float4 a  = *(const float4*)(w0 + 4*j);
            float4 b4 = *(const float4*)(w1 + 4*j);
            acc[4*j+0] = fmaf(x1, b4.x, fmaf(x0, a.x, acc[4*j+0]));
            acc[4*j+1] = fmaf(x1, b4.y, fmaf(x0, a.y, acc[4*j+1]));
            acc[4*j+2] = fmaf(x1, b4.z, fmaf(x0, a.z, acc[4*j+2]));
            acc[4*j+3] = fmaf(x1, b4.w, fmaf(x0, a.w, acc[4*j+3]));
        }
    }
}

__device__ __forceinline__ void ln_store(const float* __restrict__ X, unsigned int* __restrict__ xnp) {
    float mu = 0.0f;
    #pragma unroll
    for (int c = 0; c < DIM; ++c) mu += X[c];
    mu *= (1.0f/DIM);
    float var = 0.0f;
    #pragma unroll
    for (int c = 0; c < DIM; ++c) { float d = X[c] - mu; var += d*d; }
    var *= (1.0f/DIM);
    float rs = rsqrtf(var + 1e-5f);
    #pragma unroll
    for (int j = 0; j < DIM/2; ++j)
        xnp[j] = pack2((X[2*j] - mu)*rs, (X[2*j+1] - mu)*rs);
}

__global__ __launch_bounds__(ROWS, 3)
void tf_fused(const int* __restrict__ toks, const float* __restrict__ temb,
              const float* __restrict__ pemb, const float* __restrict__ gWq,
              const float* __restrict__ gWk, const float* __restrict__ gWv,
              const float* __restrict__ gWo, const float* __restrict__ gW1,
              const float* __restrict__ gW2, float* __restrict__ out)
{
    __shared__ float sW[2048];               //  8.0 KB weight staging (double-purpose)
    __shared__ float sTok[VOC*33];           //  pad 33 to spread banks
    __shared__ float sPos[SEQ*33];
    __shared__ unsigned int sXn[ROWS*XNP];   //  per-row private Xn / O scratch (bf16)
    __shared__ unsigned int sKV[2*ROWS*KVP]; //  K,V (cross-row) ; reused as H in FFN

    const int tid = threadIdx.x;
    const int r   = tid;                 // row within block
    const int s   = r % SEQ;
    const int rb  = r - s;               // element base row
    const long long grow = (long long)blockIdx.x * ROWS + r;

    for (int i = tid; i < VOC*DIM; i += ROWS) sTok[(i>>5)*33 + (i&31)] = temb[i];
    for (int i = tid; i < SEQ*DIM; i += ROWS) sPos[(i>>5)*33 + (i&31)] = pemb[i];
    const int tok = toks[grow];
    __syncthreads();

    float X[DIM];                        // residual stream lives in registers (f32 exact)
    #pragma unroll
    for (int c = 0; c < DIM; ++c) X[c] = sTok[tok*33 + c] + sPos[s*33 + c];

    unsigned int* const xnp = sXn + r*XNP;
    ln_store(X, xnp);                    // Xn for layer 0

    #pragma unroll 1
    for (int L = 0; L < NL; ++L) {
        const float* wqL = gWq + L*DIM*DIM;
        const float* wkL = gWk + L*DIM*DIM;
        const float* wvL = gWv + L*DIM*DIM;
        const float* woL = gWo + L*DIM*DIM;
        const float* w1L = gW1 + L*DIM*HID;
        const float* w2L = gW2 + L*HID*DIM;

        // ---- K,V projections ----
        __syncthreads();                               // prior readers of sW/sKV done
        for (int i = tid; i < DIM*DIM; i += ROWS) { sW[i] = wkL[i]; sW[DIM*DIM + i] = wvL[i]; }
        __syncthreads();
        {
            float tmp[DIM];
            gemm_row<DIM, false>(xnp, DIM/2, sW, DIM, tmp);
            unsigned int* kp = sKV + r*KVP;
            #pragma unroll
            for (int j = 0; j < DIM/2; ++j) kp[j] = pack2(tmp[2*j], tmp[2*j+1]);
            gemm_row<DIM, false>(xnp, DIM/2, sW + DIM*DIM, DIM, tmp);
            unsigned int* vp = sKV + VOFF + r*KVP;
            #pragma unroll
            for (int j = 0; j < DIM/2; ++j) vp[j] = pack2(tmp[2*j], tmp[2*j+1]);
        }
        __syncthreads();                               // publish K,V; free sW
        for (int i = tid; i < DIM*DIM; i += ROWS) { sW[i] = wqL[i]; sW[DIM*DIM + i] = woL[i]; }
        __syncthreads();
        {
            // ---- Q projection + causal attention (per-row, VALU) ----
            float Q[DIM];
            gemm_row<DIM, false>(xnp, DIM/2, sW, DIM, Q);
            float O[DIM];
            #pragma unroll
            for (int c = 0; c < DIM; ++c) O[c] = 0.0f;
            #pragma unroll
            for (int h = 0; h < NH; ++h) {
                float p[SEQ];
                float mx = -3.0e38f;
                #pragma unroll
                for (int t = 0; t < SEQ; ++t) if (t <= s) {
                    const unsigned int* kp = sKV + (rb + t)*KVP + h*4;
                    uint2 ka = *(const uint2*)kp;
                    uint2 kb = *(const uint2*)(kp + 2);
                    float sc = Q[h*8+0]*bf_lo(ka.x) + Q[h*8+1]*bf_hi(ka.x)
                             + Q[h*8+2]*bf_lo(ka.y) + Q[h*8+3]*bf_hi(ka.y)
                             + Q[h*8+4]*bf_lo(kb.x) + Q[h*8+5]*bf_hi(kb.x)
                             + Q[h*8+6]*bf_lo(kb.y) + Q[h*8+7]*bf_hi(kb.y);
                    sc *= 0.35355339059327373f;        // 1/sqrt(DH)
                    p[t] = sc;
                    mx = fmaxf(mx, sc);
                }
                float den = 0.0f;
                #pragma unroll
                for (int t = 0; t < SEQ; ++t) if (t <= s) {
                    float e = __expf(p[t] - mx);
                    p[t] = e; den += e;
                }
                float rden = 1.0f / den;
                #pragma unroll
                for (int t = 0; t < SEQ; ++t) if (t <= s) {
                    float wgt = p[t] * rden;
                    const unsigned int* vp = sKV + VOFF + (rb + t)*KVP + h*4;
                    uint2 va = *(const uint2*)vp;
                    uint2 vb = *(const uint2*)(vp + 2);
                    O[h*8+0] = fmaf(wgt, bf_lo(va.x), O[h*8+0]);
                    O[h*8+1] = fmaf(wgt, bf_hi(va.x), O[h*8+1]);
                    O[h*8+2] = fmaf(wgt, bf_lo(va.y), O[h*8+2]);
                    O[h*8+3] = fmaf(wgt, bf_hi(va.y), O[h*8+3]);
                    O[h*8+4] = fmaf(wgt, bf_lo(vb.x), O[h*8+4]);
                    O[h*8+5] = fmaf(wgt, bf_hi(vb.x), O[h*8+5]);
                    O[h*8+6] = fmaf(wgt, bf_lo(vb.y), O[h*8+6]);
                    O[h*8+7] = fmaf(wgt, bf_hi(vb.y), O[h*8+7]);
                }
            }
            // O -> own sXn row (Xn1 dead), then X += O*Wo, then LN2 -> sXn
            #pragma unroll
            for (int j = 0; j < DIM/2; ++j) xnp[j] = pack2(O[2*j], O[2*j+1]);
            gemm_row<DIM, true>(xnp, DIM/2, sW + DIM*DIM, DIM, X);
            ln_store(X, xnp);
        }
        __syncthreads();                               // sW(Wq,Wo) and sKV(attn) free

        // ---- FFN in two hidden halves (8 KB sW budget) ----
        #pragma unroll 1
        for (int half = 0; half < 2; ++half) {
            for (int i = tid; i < 2048; i += ROWS)
                sW[i] = w1L[(i>>6)*HID + half*64 + (i&63)];
            __syncthreads();
            float hb[64];
            gemm_row<64, false>(xnp, DIM/2, sW, 64, hb);
            #pragma unroll
            for (int e = 0; e < 64; ++e)               // exact GELU (erf)
                hb[e] = 0.5f*hb[e]*(1.0f + erff(hb[e]*0.7071067811865475f));
            unsigned int* hp = sKV + r*SHP;            // reuse KV region (dead) as H
            #pragma unroll
            for (int j = 0; j < 32; ++j) hp[j] = pack2(hb[2*j], hb[2*j+1]);
            __syncthreads();                           // sW free (W1 reads done)
            for (int i = tid; i < 2048; i += ROWS)
                sW[i] = w2L[half*2048 + i];
            __syncthreads();
            gemm_row<DIM, true>(hp, 32, sW, DIM, X);   // X += H_half * W2_half
            __syncthreads();                           // before next half overwrites sW
        }
        ln_store(X, xnp);                              // Xn for next layer, or final LN
    }

    // ---- logits = LN(X) . tok_emb^T  (weight tying; sTok broadcast reads) ----
    float lg[VOC];
    #pragma unroll
    for (int v = 0; v < VOC; ++v) lg[v] = 0.0f;
    #pragma unroll 1
    for (int dp = 0; dp < DIM/2; ++dp) {
        unsigned int u = xnp[dp];
        float x0 = bf_lo(u), x1 = bf_hi(u);
        #pragma unroll
        for (int v = 0; v < VOC; ++v)
            lg[v] = fmaf(x1, sTok[v*33 + 2*dp + 1], fmaf(x0, sTok[v*33 + 2*dp], lg[v]));
    }
    float* op = out + grow*VOC;
    #pragma unroll
    for (int v = 0; v < VOC; ++v) op[v] = lg[v];
}

extern "C" void kernel_launch(void* const* d_in, const int* in_sizes, int n_in,
                              void* d_out, int out_size, void* d_ws, size_t ws_size,
                              hipStream_t stream) {
    const int*   toks = (const int*)  d_in[0];
    const float* temb = (const float*)d_in[1];
    const float* pemb = (const float*)d_in[2];
    const float* wq   = (const float*)d_in[3];
    const float* wk   = (const float*)d_in[4];
    const float* wv   = (const float*)d_in[5];
    const float* wo   = (const float*)d_in[6];
    const float* w1   = (const float*)d_in[7];
    const float* w2   = (const float*)d_in[8];
    float* out = (float*)d_out;
    const int batch = in_sizes[0] / SEQ;     // 131072
    const int nblk  = batch / EPB;           // 4096
    tf_fused<<<dim3(nblk), dim3(ROWS), 0, stream>>>(toks, temb, pemb, wq, wk, wv, wo, w1, w2, out);
}

// Round 2
// 469.063 us; speedup vs baseline: 2.9544x; 2.9544x over previous
//
#include <hip/hip_runtime.h>

#define SEQ 6
#define EPB 32
#define ROWS 192                 // threads = activation rows per block (3 waves)
#define NL 2
#define VOC 15

typedef __attribute__((ext_vector_type(8))) short bf16x8;   // 8 bf16 = 4 VGPRs
typedef __attribute__((ext_vector_type(4))) float f32x4;

// LDS pool offsets (u32 units). Total 13440 u32 = 52.5 KB -> 3 blocks/CU.
#define XN 0        // 192*20: Xn -> Q -> O -> Xn2  (all own-wave/own-row reuse)
#define KP 3840     // 192*20: K -> H(quarter) -> logits f32 out
#define VP 7680     // 192*20: V -> OWo out -> FFN2 out
#define WT 11520    // 1920: rotating sigma-packed transposed weights
#define SMEM_U32 13440
#define STA 20      // activation row stride (u32): 80B, 16B-aligned, bank-spread
#define STW 20      // weight col stride (u32)

__device__ __forceinline__ unsigned int pack2(float a, float b) {
    unsigned int ua = __float_as_uint(a), ub = __float_as_uint(b);
    ua += 0x7fffu + ((ua >> 16) & 1u);   // RNE to bf16
    ub += 0x7fffu + ((ub >> 16) & 1u);
    return (ua >> 16) | (ub & 0xffff0000u);
}
__device__ __forceinline__ float bf_lo(unsigned int u){ return __uint_as_float(u << 16); }
__device__ __forceinline__ float bf_hi(unsigned int u){ return __uint_as_float(u & 0xffff0000u); }

__device__ __forceinline__ bf16x8 ldf(const unsigned int* S, int idx) {
    union { uint4 u; bf16x8 h; } t;
    t.u = *(const uint4*)&S[idx];
    return t.h;
}
__device__ __forceinline__ float gelu(float x) {
    return 0.5f * x * (1.0f + erff(x * 0.70710678118654752f));
}
// LN(X) -> sigma-packed bf16 row (word w = cols (w, w+16))
__device__ __forceinline__ void ln_write(const float* X, unsigned int* dst) {
    float mu = 0.f;
    #pragma unroll
    for (int c = 0; c < 32; ++c) mu += X[c];
    mu *= 0.03125f;
    float var = 0.f;
    #pragma unroll
    for (int c = 0; c < 32; ++c) { float d = X[c] - mu; var += d * d; }
    var *= 0.03125f;
    float rs = rsqrtf(var + 1e-5f);
    #pragma unroll
    for (int g = 0; g < 4; ++g) {
        uint4 w;
        w.x = pack2((X[4*g+0]-mu)*rs, (X[16+4*g+0]-mu)*rs);
        w.y = pack2((X[4*g+1]-mu)*rs, (X[16+4*g+1]-mu)*rs);
        w.z = pack2((X[4*g+2]-mu)*rs, (X[16+4*g+2]-mu)*rs);
        w.w = pack2((X[4*g+3]-mu)*rs, (X[16+4*g+3]-mu)*rs);
        *(uint4*)(dst + 4*g) = w;
    }
}
// unpack sigma-packed row -> 32 floats
__device__ __forceinline__ void unpack_row(const unsigned int* p, float* f) {
    uint4 a = *(const uint4*)p, b = *(const uint4*)(p+4);
    uint4 c = *(const uint4*)(p+8), d = *(const uint4*)(p+12);
    #define UNPK(u,i) f[i]=bf_lo(u); f[16+(i)]=bf_hi(u);
    UNPK(a.x,0) UNPK(a.y,1) UNPK(a.z,2) UNPK(a.w,3)
    UNPK(b.x,4) UNPK(b.y,5) UNPK(b.z,6) UNPK(b.w,7)
    UNPK(c.x,8) UNPK(c.y,9) UNPK(c.z,10) UNPK(c.w,11)
    UNPK(d.x,12) UNPK(d.y,13) UNPK(d.z,14) UNPK(d.w,15)
    #undef UNPK
}

__global__ __launch_bounds__(ROWS, 2)
void tf_mfma(const int* __restrict__ toks, const float* __restrict__ temb,
             const float* __restrict__ pemb, const float* __restrict__ gWq,
             const float* __restrict__ gWk, const float* __restrict__ gWv,
             const float* __restrict__ gWo, const float* __restrict__ gW1,
             const float* __restrict__ gW2, float* __restrict__ out)
{
    __shared__ unsigned int S[SMEM_U32];
    const int tid  = threadIdx.x;
    const int lane = tid & 63;
    const int wid  = tid >> 6;
    const int llo  = lane & 15, lhi = lane >> 4;
    const int s    = tid % SEQ;
    const int rb   = tid - s;                    // element base row
    const long long gbase = (long long)blockIdx.x * ROWS;
    const f32x4 zz = {0.f, 0.f, 0.f, 0.f};

    // ---- X init from embeddings (one-time, L2-resident tables) ----
    float X[32];
    {
        const int tok = toks[gbase + tid];
        #pragma unroll
        for (int c = 0; c < 32; ++c) X[c] = temb[tok*32 + c] + pemb[s*32 + c];
    }

    #pragma unroll 1
    for (int L = 0; L < NL; ++L) {
        const float* wqL = gWq + L*1024;
        const float* wkL = gWk + L*1024;
        const float* wvL = gWv + L*1024;
        const float* woL = gWo + L*1024;
        const float* w1L = gW1 + L*32*128;
        const float* w2L = gW2 + L*128*32;

        __syncthreads();                                        // B1: WT + pools free
        ln_write(X, &S[XN + tid*STA]);                          // Xn (layer input LN)
        for (int i = tid; i < 1536; i += ROWS) {                // stage WqT,WkT,WvT
            int wsel = i >> 9, r = i & 511;
            int c = r >> 4, w = r & 15;
            const float* g = wsel == 0 ? wqL : (wsel == 1 ? wkL : wvL);
            S[WT + wsel*640 + c*STW + w] = pack2(g[w*32 + c], g[(w+16)*32 + c]);
        }
        __syncthreads();                                        // B2

        // ---- QKV via MFMA ----
        {
            bf16x8 bq0 = ldf(S, WT +        llo*STW + 4*lhi);
            bf16x8 bq1 = ldf(S, WT +   (16+llo)*STW + 4*lhi);
            bf16x8 bk0 = ldf(S, WT + 640 +      llo*STW + 4*lhi);
            bf16x8 bk1 = ldf(S, WT + 640 + (16+llo)*STW + 4*lhi);
            bf16x8 bv0 = ldf(S, WT + 1280+      llo*STW + 4*lhi);
            bf16x8 bv1 = ldf(S, WT + 1280+ (16+llo)*STW + 4*lhi);
            f32x4 qf[4][2], kf[4][2], vf[4][2];
            #pragma unroll
            for (int j = 0; j < 4; ++j) {
                bf16x8 a = ldf(S, XN + (wid*64 + j*16 + llo)*STA + 4*lhi);
                qf[j][0] = __builtin_amdgcn_mfma_f32_16x16x32_bf16(a, bq0, zz, 0,0,0);
                qf[j][1] = __builtin_amdgcn_mfma_f32_16x16x32_bf16(a, bq1, zz, 0,0,0);
                kf[j][0] = __builtin_amdgcn_mfma_f32_16x16x32_bf16(a, bk0, zz, 0,0,0);
                kf[j][1] = __builtin_amdgcn_mfma_f32_16x16x32_bf16(a, bk1, zz, 0,0,0);
                vf[j][0] = __builtin_amdgcn_mfma_f32_16x16x32_bf16(a, bv0, zz, 0,0,0);
                vf[j][1] = __builtin_amdgcn_mfma_f32_16x16x32_bf16(a, bv1, zz, 0,0,0);
            }
            #pragma unroll
            for (int j = 0; j < 4; ++j) {
                int rowb = wid*64 + j*16 + lhi*4;
                #pragma unroll
                for (int rg = 0; rg < 4; ++rg) {
                    S[XN + (rowb+rg)*STA + llo] = pack2(qf[j][0][rg], qf[j][1][rg]); // Q over Xn (own wave)
                    S[KP + (rowb+rg)*STA + llo] = pack2(kf[j][0][rg], kf[j][1][rg]);
                    S[VP + (rowb+rg)*STA + llo] = pack2(vf[j][0][rg], vf[j][1][rg]);
                }
            }
        }
        __syncthreads();                                        // B3: K,V visible cross-wave

        // ---- attention (per-thread row, VALU) + stage WoT ----
        {
            for (int i = tid; i < 512; i += ROWS) {             // stage Wo
                int c = i >> 4, w = i & 15;
                S[WT + c*STW + w] = pack2(woL[w*32 + c], woL[(w+16)*32 + c]);
            }
            float Qv[32];
            unpack_row(&S[XN + tid*STA], Qv);
            float p[4][SEQ], mx[4], den[4], O[32];
            #pragma unroll
            for (int h = 0; h < 4; ++h) { mx[h] = -3.0e38f; den[h] = 0.f; }
            #pragma unroll
            for (int c = 0; c < 32; ++c) O[c] = 0.f;
            #pragma unroll
            for (int t = 0; t < SEQ; ++t) if (t <= s) {
                float Kf[32];
                unpack_row(&S[KP + (rb+t)*STA], Kf);
                #pragma unroll
                for (int h = 0; h < 4; ++h) {
                    float sc = 0.f;
                    #pragma unroll
                    for (int d = 0; d < 8; ++d) sc += Qv[h*8+d] * Kf[h*8+d];
                    sc *= 0.35355339059327373f;
                    p[h][t] = sc; mx[h] = fmaxf(mx[h], sc);
                }
            }
            #pragma unroll
            for (int t = 0; t < SEQ; ++t) if (t <= s) {
                #pragma unroll
                for (int h = 0; h < 4; ++h) {
                    float e = __expf(p[h][t] - mx[h]);
                    p[h][t] = e; den[h] += e;
                }
            }
            float rden[4];
            #pragma unroll
            for (int h = 0; h < 4; ++h) rden[h] = 1.f / den[h];
            #pragma unroll
            for (int t = 0; t < SEQ; ++t) if (t <= s) {
                float Vf[32];
                unpack_row(&S[VP + (rb+t)*STA], Vf);
                #pragma unroll
                for (int h = 0; h < 4; ++h) {
                    float wgt = p[h][t] * rden[h];
                    #pragma unroll
                    for (int d = 0; d < 8; ++d) O[h*8+d] = fmaf(wgt, Vf[h*8+d], O[h*8+d]);
                }
            }
            #pragma unroll
            for (int w = 0; w < 16; ++w)                        // O over Q (own row)
                S[XN + tid*STA + w] = pack2(O[w], O[w+16]);
        }
        __syncthreads();                                        // B4

        // ---- O . Wo via MFMA -> VP ----
        {
            bf16x8 bo0 = ldf(S, WT +      llo*STW + 4*lhi);
            bf16x8 bo1 = ldf(S, WT + (16+llo)*STW + 4*lhi);
            f32x4 oo[4][2];
            #pragma unroll
            for (int j = 0; j < 4; ++j) {
                bf16x8 a = ldf(S, XN + (wid*64 + j*16 + llo)*STA + 4*lhi);
                oo[j][0] = __builtin_amdgcn_mfma_f32_16x16x32_bf16(a, bo0, zz, 0,0,0);
                oo[j][1] = __builtin_amdgcn_mfma_f32_16x16x32_bf16(a, bo1, zz, 0,0,0);
            }
            #pragma unroll
            for (int j = 0; j < 4; ++j) {
                int rowb = wid*64 + j*16 + lhi*4;
                #pragma unroll
                for (int rg = 0; rg < 4; ++rg)
                    S[VP + (rowb+rg)*STA + llo] = pack2(oo[j][0][rg], oo[j][1][rg]);
            }
        }
        // residual + LN2 (own wave: no barrier needed before these reads/writes)
        #pragma unroll
        for (int w = 0; w < 16; ++w) {
            unsigned int u = S[VP + tid*STA + w];
            X[w] += bf_lo(u); X[w+16] += bf_hi(u);
        }
        ln_write(X, &S[XN + tid*STA]);                          // Xn2

        // ---- FFN in 4 column-quarters, FFN2 accumulates in regs ----
        f32x4 cf[4][2];
        #pragma unroll
        for (int j = 0; j < 4; ++j) { cf[j][0] = zz; cf[j][1] = zz; }
        #pragma unroll 1
        for (int qr = 0; qr < 4; ++qr) {
            __syncthreads();                                    // WT free (all waves)
            for (int i = tid; i < 512; i += ROWS) {             // stage W1 quarter
                int c = i >> 4, w = i & 15;
                S[WT + c*STW + w] =
                    pack2(w1L[w*128 + 32*qr + c], w1L[(w+16)*128 + 32*qr + c]);
            }
            for (int i = tid; i < 512; i += ROWS) {             // stage W2 quarter
                int c = i >> 4, w = i & 15;
                S[WT + 640 + c*STW + w] =
                    pack2(w2L[(32*qr+w)*32 + c], w2L[(32*qr+16+w)*32 + c]);
            }
            __syncthreads();
            bf16x8 b10 = ldf(S, WT +            llo*STW + 4*lhi);
            bf16x8 b11 = ldf(S, WT +       (16+llo)*STW + 4*lhi);
            bf16x8 b20 = ldf(S, WT + 640 +      llo*STW + 4*lhi);
            bf16x8 b21 = ldf(S, WT + 640 + (16+llo)*STW + 4*lhi);
            f32x4 ha[4][2];
            #pragma unroll
            for (int j = 0; j < 4; ++j) {
                bf16x8 a = ldf(S, XN + (wid*64 + j*16 + llo)*STA + 4*lhi);
                ha[j][0] = __builtin_amdgcn_mfma_f32_16x16x32_bf16(a, b10, zz, 0,0,0);
                ha[j][1] = __builtin_amdgcn_mfma_f32_16x16x32_bf16(a, b11, zz, 0,0,0);
            }
            #pragma unroll
            for (int j = 0; j < 4; ++j) {                       // GELU + write H (own wave)
                int rowb = wid*64 + j*16 + lhi*4;
                #pragma unroll
                for (int rg = 0; rg < 4; ++rg)
                    S[KP + (rowb+rg)*STA + llo] =
                        pack2(gelu(ha[j][0][rg]), gelu(ha[j][1][rg]));
            }
            #pragma unroll
            for (int j = 0; j < 4; ++j) {                       // FFN2 quarter (own-wave H)
                bf16x8 a = ldf(S, KP + (wid*64 + j*16 + llo)*STA + 4*lhi);
                cf[j][0] = __builtin_amdgcn_mfma_f32_16x16x32_bf16(a, b20, cf[j][0], 0,0,0);
                cf[j][1] = __builtin_amdgcn_mfma_f32_16x16x32_bf16(a, b21, cf[j][1], 0,0,0);
            }
        }
        #pragma unroll
        for (int j = 0; j < 4; ++j) {                           // FFN2 out -> VP
            int rowb = wid*64 + j*16 + lhi*4;
            #pragma unroll
            for (int rg = 0; rg < 4; ++rg)
                S[VP + (rowb+rg)*STA + llo] = pack2(cf[j][0][rg], cf[j][1][rg]);
        }
        #pragma unroll
        for (int w = 0; w < 16; ++w) {                          // residual (own wave)
            unsigned int u = S[VP + tid*STA + w];
            X[w] += bf_lo(u); X[w+16] += bf_hi(u);
        }
    }

    // ---- final LN + logits (weight-tied) ----
    __syncthreads();                                            // BL1: WT free
    ln_write(X, &S[XN + tid*STA]);
    for (int i = tid; i < 256; i += ROWS) {                     // stage TE^T (16 cols, pad)
        int n = i >> 4, w = i & 15;
        unsigned int val = 0u;
        if (n < VOC) val = pack2(temb[n*32 + w], temb[n*32 + w + 16]);
        S[WT + n*STW + w] = val;
    }
    __syncthreads();                                            // BL2
    {
        bf16x8 bt = ldf(S, WT + llo*STW + 4*lhi);
        f32x4 lg[4];
        #pragma unroll
        for (int j = 0; j < 4; ++j) {
            bf16x8 a = ldf(S, XN + (wid*64 + j*16 + llo)*STA + 4*lhi);
            lg[j] = __builtin_amdgcn_mfma_f32_16x16x32_bf16(a, bt, zz, 0,0,0);
        }
        #pragma unroll
        for (int j = 0; j < 4; ++j) {
            int rowb = wid*64 + j*16 + lhi*4;
            #pragma unroll
            for (int rg = 0; rg < 4; ++rg)
                S[KP + (rowb+rg)*17 + llo] = __float_as_uint(lg[j][rg]);
        }
    }
    __syncthreads();                                            // BL3
    #pragma unroll
    for (int i = 0; i < VOC; ++i) {                             // coalesced output
        int flat = tid + ROWS*i;
        int row = flat / VOC, col = flat % VOC;
        out[gbase*VOC + flat] = __uint_as_float(S[KP + row*17 + col]);
    }
}

extern "C" void kernel_launch(void* const* d_in, const int* in_sizes, int n_in,
                              void* d_out, int out_size, void* d_ws, size_t ws_size,
                              hipStream_t stream) {
    const int*   toks = (const int*)  d_in[0];
    const float* temb = (const float*)d_in[1];
    const float* pemb = (const float*)d_in[2];
    const float* wq   = (const float*)d_in[3];
    const float* wk   = (const float*)d_in[4];
    const float* wv   = (const float*)d_in[5];
    const float* wo   = (const float*)d_in[6];
    const float* w1   = (const float*)d_in[7];
    const float* w2   = (const float*)d_in[8];
    float* out = (float*)d_out;
    const int batch = in_sizes[0] / SEQ;     // 131072
    const int nblk  = batch / EPB;           // 4096
    tf_mfma<<<dim3(nblk), dim3(ROWS), 0, stream>>>(toks, temb, pemb, wq, wk, wv, wo, w1, w2, out);
}

// Round 3
// 246.880 us; speedup vs baseline: 5.6133x; 1.9000x over previous
//
#include <hip/hip_runtime.h>

#define SEQ 6
#define ROWS 192                 // 3 waves; thread = one (elem,seq) row
#define NL 2
#define VOC 15

typedef __attribute__((ext_vector_type(8))) _Float16 h8;
typedef __attribute__((ext_vector_type(2))) _Float16 h2;
typedef __attribute__((ext_vector_type(4))) float    f32x4;

// LDS pools (u32 words). stride 16/row, packed. Total 11776 u32 = 46 KB -> 3 blocks/CU.
#define XN   0        // 192*16: Xn -> Q -> O -> Xn2
#define KPP  3072     // 192*16: K -> H(quarter) -> logits f32
#define VPP  6144     // 192*16: V -> OWo out -> FFN2 out
#define WT0  9216     // 1536: QKV tiles / even FFN quarters / TE
#define WT1  10752    // 1024: Wo / odd FFN quarters
#define SMEM_U32 11776

// ws layout (u32): per layer L at L*6144: Wq 0, Wk 512, Wv 1024, Wo 1536,
// quarter q: 2048+q*1024 (W1q at +0, W2q at +512). TE at 12288 (256). Total 12544.

__device__ __forceinline__ unsigned int pkh(float a, float b) {
    auto h = __builtin_amdgcn_cvt_pkrtz(a, b);       // v_cvt_pkrtz_f16_f32, 1 inst
    return __builtin_bit_cast(unsigned int, h);
}
__device__ __forceinline__ float lo16(unsigned int u) {
    h2 h = __builtin_bit_cast(h2, u); return (float)h.x;
}
__device__ __forceinline__ float hi16(unsigned int u) {
    h2 h = __builtin_bit_cast(h2, u); return (float)h.y;
}
__device__ __forceinline__ h8 ldh(const unsigned int* p) {
    uint4 u = *(const uint4*)p;
    return __builtin_bit_cast(h8, u);
}
#if __has_builtin(__builtin_amdgcn_fdot2)
__device__ __forceinline__ float dot2acc(unsigned int a, unsigned int b, float c) {
    return __builtin_amdgcn_fdot2(__builtin_bit_cast(h2, a), __builtin_bit_cast(h2, b), c, false);
}
#else
__device__ __forceinline__ float dot2acc(unsigned int a, unsigned int b, float c) {
    return fmaf(hi16(a), hi16(b), fmaf(lo16(a), lo16(b), c));
}
#endif
__device__ __forceinline__ float gelu_f(float x) {   // tanh-form, 6 inst
    float t = x * x;
    float v = x * fmaf(0.0713548162726f, t, 1.5957691216057308f);
    return x * __builtin_amdgcn_rcpf(1.0f + __expf(-v));
}
// head permutation: permuted col p -> original col (makes sigma-pairs head-local)
__device__ __forceinline__ int permc(int p) {
    int h = (p & 15) >> 2, j = p & 3, hi = p >> 4;
    return 8*h + 2*j + hi;
}
__device__ __forceinline__ void ln_write(const float* X, unsigned int* dst) {
    float mu = 0.f;
    #pragma unroll
    for (int c = 0; c < 32; ++c) mu += X[c];
    mu *= 0.03125f;
    float var = 0.f;
    #pragma unroll
    for (int c = 0; c < 32; ++c) { float d = X[c] - mu; var += d * d; }
    var *= 0.03125f;
    float rs = rsqrtf(var + 1e-5f), b = -mu * rs;
    #pragma unroll
    for (int g = 0; g < 4; ++g) {
        uint4 w;
        w.x = pkh(fmaf(X[4*g+0], rs, b), fmaf(X[16+4*g+0], rs, b));
        w.y = pkh(fmaf(X[4*g+1], rs, b), fmaf(X[16+4*g+1], rs, b));
        w.z = pkh(fmaf(X[4*g+2], rs, b), fmaf(X[16+4*g+2], rs, b));
        w.w = pkh(fmaf(X[4*g+3], rs, b), fmaf(X[16+4*g+3], rs, b));
        *(uint4*)(dst + 4*g) = w;
    }
}

// ---- prep: pre-pack all weights (f16, transposed, head-permuted) into ws ----
__global__ __launch_bounds__(64) void prep(
    const float* __restrict__ temb, const float* __restrict__ wq,
    const float* __restrict__ wk, const float* __restrict__ wv,
    const float* __restrict__ wo, const float* __restrict__ w1,
    const float* __restrict__ w2, unsigned int* __restrict__ ws)
{
    const int part = blockIdx.x;          // 0..24
    const int t = threadIdx.x;
    if (part == 24) {                     // TE tile: 16 cols x 16 words (col 15 zero)
        for (int i = t; i < 256; i += 64) {
            int c = i >> 4, w = i & 15;
            ws[12288 + i] = (c < VOC) ? pkh(temb[c*32 + w], temb[c*32 + w + 16]) : 0u;
        }
        return;
    }
    const int L = part / 12, m = part % 12;
    unsigned int* o = ws + L * 6144;
    for (int i = t; i < 512; i += 64) {
        int c = i >> 4, w = i & 15;
        if (m < 3) {                      // WqT/WkT/WvT, head-permuted output cols
            const float* M = (m == 0 ? wq : (m == 1 ? wk : wv)) + L*1024;
            int pc = permc(c);
            o[m*512 + i] = pkh(M[w*32 + pc], M[(w+16)*32 + pc]);
        } else if (m == 3) {              // WoT, head-permuted input rows
            const float* M = wo + L*1024;
            o[1536 + i] = pkh(M[permc(w)*32 + c], M[permc(w+16)*32 + c]);
        } else if (m < 8) {               // W1 quarter q
            int q = m - 4;
            const float* M = w1 + L*4096;
            o[2048 + q*1024 + i] = pkh(M[w*128 + 32*q + c], M[(w+16)*128 + 32*q + c]);
        } else {                          // W2 quarter q
            int q = m - 8;
            const float* M = w2 + L*4096;
            o[2048 + q*1024 + 512 + i] = pkh(M[(32*q+w)*32 + c], M[(32*q+16+w)*32 + c]);
        }
    }
}

__global__ __launch_bounds__(ROWS, 2)
void tf_mfma(const int* __restrict__ toks, const float* __restrict__ temb,
             const float* __restrict__ pemb, const unsigned int* __restrict__ ws,
             float* __restrict__ out)
{
    __shared__ unsigned int S[SMEM_U32];
    const int tid  = threadIdx.x;
    const int lane = tid & 63;
    const int wid  = tid >> 6;
    const int llo  = lane & 15, lhi = lane >> 4;
    const int boff = 4 * lhi;
    const int s    = tid % SEQ;
    const int rb   = tid - s;
    const long long gbase = (long long)blockIdx.x * ROWS;
    const f32x4 zz = {0.f, 0.f, 0.f, 0.f};

    float X[32];
    {
        const int tok = toks[gbase + tid];
        #pragma unroll
        for (int g = 0; g < 8; ++g) {
            float4 a = *(const float4*)&temb[tok*32 + 4*g];
            float4 b = *(const float4*)&pemb[s*32 + 4*g];
            X[4*g+0] = a.x + b.x; X[4*g+1] = a.y + b.y;
            X[4*g+2] = a.z + b.z; X[4*g+3] = a.w + b.w;
        }
    }

    #pragma unroll 1
    for (int L = 0; L < NL; ++L) {
        const unsigned int* wsL = ws + L * 6144;

        ln_write(X, &S[XN + tid*16]);                    // Xn (own row)
        for (int i = tid; i < 1536; i += ROWS) S[WT0 + i] = wsL[i];   // QKV tiles
        __syncthreads();                                 // B1

        // ---- QKV MFMA ----
        {
            h8 bq0 = ldh(&S[WT0 +        (llo   )*16 + boff]);
            h8 bq1 = ldh(&S[WT0 +        (llo+16)*16 + boff]);
            h8 bk0 = ldh(&S[WT0 +  512 + (llo   )*16 + boff]);
            h8 bk1 = ldh(&S[WT0 +  512 + (llo+16)*16 + boff]);
            h8 bv0 = ldh(&S[WT0 + 1024 + (llo   )*16 + boff]);
            h8 bv1 = ldh(&S[WT0 + 1024 + (llo+16)*16 + boff]);
            f32x4 qf[4][2], kf[4][2], vf[4][2];
            #pragma unroll
            for (int j = 0; j < 4; ++j) {
                h8 a = ldh(&S[XN + (wid*64 + j*16 + llo)*16 + boff]);
                qf[j][0] = __builtin_amdgcn_mfma_f32_16x16x32_f16(a, bq0, zz, 0,0,0);
                qf[j][1] = __builtin_amdgcn_mfma_f32_16x16x32_f16(a, bq1, zz, 0,0,0);
                kf[j][0] = __builtin_amdgcn_mfma_f32_16x16x32_f16(a, bk0, zz, 0,0,0);
                kf[j][1] = __builtin_amdgcn_mfma_f32_16x16x32_f16(a, bk1, zz, 0,0,0);
                vf[j][0] = __builtin_amdgcn_mfma_f32_16x16x32_f16(a, bv0, zz, 0,0,0);
                vf[j][1] = __builtin_amdgcn_mfma_f32_16x16x32_f16(a, bv1, zz, 0,0,0);
            }
            #pragma unroll
            for (int j = 0; j < 4; ++j) {
                int rowb = wid*64 + j*16 + lhi*4;
                #pragma unroll
                for (int rg = 0; rg < 4; ++rg) {
                    S[XN  + (rowb+rg)*16 + llo] = pkh(qf[j][0][rg], qf[j][1][rg]);
                    S[KPP + (rowb+rg)*16 + llo] = pkh(kf[j][0][rg], kf[j][1][rg]);
                    S[VPP + (rowb+rg)*16 + llo] = pkh(vf[j][0][rg], vf[j][1][rg]);
                }
            }
        }
        __syncthreads();                                 // B2: K,V published

        // ---- stage Wo + FFN q0 (free slots) + per-row attention ----
        {
            for (int i = tid; i < 512;  i += ROWS) S[WT1 + i] = wsL[1536 + i];
            for (int i = tid; i < 1024; i += ROWS) S[WT0 + i] = wsL[2048 + i];

            uint4 q4[4];
            #pragma unroll
            for (int h = 0; h < 4; ++h) q4[h] = *(const uint4*)&S[XN + tid*16 + 4*h];

            float p[4][SEQ];
            #pragma unroll
            for (int t = 0; t < SEQ; ++t) {
                const unsigned int* kr = &S[KPP + (rb + t)*16];
                float msk = (t <= s) ? 0.f : -1e30f;
                #pragma unroll
                for (int h = 0; h < 4; ++h) {
                    uint4 kk = *(const uint4*)(kr + 4*h);
                    float d = dot2acc(q4[h].x, kk.x, 0.f);
                    d = dot2acc(q4[h].y, kk.y, d);
                    d = dot2acc(q4[h].z, kk.z, d);
                    d = dot2acc(q4[h].w, kk.w, d);
                    p[h][t] = fmaf(d, 0.35355339059327373f, msk);
                }
            }
            float rd[4];
            #pragma unroll
            for (int h = 0; h < 4; ++h) {
                float mx = p[h][0];
                #pragma unroll
                for (int t = 1; t < SEQ; ++t) mx = fmaxf(mx, p[h][t]);
                float den = 0.f;
                #pragma unroll
                for (int t = 0; t < SEQ; ++t) {
                    float e = __expf(p[h][t] - mx);
                    p[h][t] = e; den += e;
                }
                rd[h] = __builtin_amdgcn_rcpf(den);
            }
            float Olo[16], Ohi[16];
            #pragma unroll
            for (int w = 0; w < 16; ++w) { Olo[w] = 0.f; Ohi[w] = 0.f; }
            #pragma unroll
            for (int t = 0; t < SEQ; ++t) {
                const unsigned int* vr = &S[VPP + (rb + t)*16];
                #pragma unroll
                for (int h = 0; h < 4; ++h) {
                    float wg = p[h][t] * rd[h];
                    uint4 vv = *(const uint4*)(vr + 4*h);
                    Olo[4*h+0] = fmaf(lo16(vv.x), wg, Olo[4*h+0]);
                    Ohi[4*h+0] = fmaf(hi16(vv.x), wg, Ohi[4*h+0]);
                    Olo[4*h+1] = fmaf(lo16(vv.y), wg, Olo[4*h+1]);
                    Ohi[4*h+1] = fmaf(hi16(vv.y), wg, Ohi[4*h+1]);
                    Olo[4*h+2] = fmaf(lo16(vv.z), wg, Olo[4*h+2]);
                    Ohi[4*h+2] = fmaf(hi16(vv.z), wg, Ohi[4*h+2]);
                    Olo[4*h+3] = fmaf(lo16(vv.w), wg, Olo[4*h+3]);
                    Ohi[4*h+3] = fmaf(hi16(vv.w), wg, Ohi[4*h+3]);
                }
            }
            #pragma unroll
            for (int g = 0; g < 4; ++g) {                // O over Q (own row)
                uint4 w;
                w.x = pkh(Olo[4*g+0], Ohi[4*g+0]);
                w.y = pkh(Olo[4*g+1], Ohi[4*g+1]);
                w.z = pkh(Olo[4*g+2], Ohi[4*g+2]);
                w.w = pkh(Olo[4*g+3], Ohi[4*g+3]);
                *(uint4*)&S[XN + tid*16 + 4*g] = w;
            }
        }
        __syncthreads();                                 // B3: Wo/q0 staged, attn reads done

        // ---- O . Wo ----
        {
            h8 bo0 = ldh(&S[WT1 + (llo   )*16 + boff]);
            h8 bo1 = ldh(&S[WT1 + (llo+16)*16 + boff]);
            f32x4 oo[4][2];
            #pragma unroll
            for (int j = 0; j < 4; ++j) {
                h8 a = ldh(&S[XN + (wid*64 + j*16 + llo)*16 + boff]);
                oo[j][0] = __builtin_amdgcn_mfma_f32_16x16x32_f16(a, bo0, zz, 0,0,0);
                oo[j][1] = __builtin_amdgcn_mfma_f32_16x16x32_f16(a, bo1, zz, 0,0,0);
            }
            #pragma unroll
            for (int j = 0; j < 4; ++j) {
                int rowb = wid*64 + j*16 + lhi*4;
                #pragma unroll
                for (int rg = 0; rg < 4; ++rg)
                    S[VPP + (rowb+rg)*16 + llo] = pkh(oo[j][0][rg], oo[j][1][rg]);
            }
        }
        #pragma unroll
        for (int g = 0; g < 4; ++g) {                    // residual (own row)
            uint4 v = *(const uint4*)&S[VPP + tid*16 + 4*g];
            X[4*g+0] += lo16(v.x); X[16+4*g+0] += hi16(v.x);
            X[4*g+1] += lo16(v.y); X[16+4*g+1] += hi16(v.y);
            X[4*g+2] += lo16(v.z); X[16+4*g+2] += hi16(v.z);
            X[4*g+3] += lo16(v.w); X[16+4*g+3] += hi16(v.w);
        }
        ln_write(X, &S[XN + tid*16]);                    // Xn2
        __syncthreads();                                 // B4: WT1 (Wo) free

        // ---- FFN: 4 column-quarters, ping-pong WT0/WT1, FFN2 accumulates ----
        f32x4 cf[4][2];
        #pragma unroll
        for (int j = 0; j < 4; ++j) { cf[j][0] = zz; cf[j][1] = zz; }
        #pragma unroll
        for (int q = 0; q < 4; ++q) {
            if (q < 3) {
                const int dst = (q & 1) ? WT0 : WT1;     // q1->WT1, q2->WT0, q3->WT1
                for (int i = tid; i < 1024; i += ROWS) S[dst + i] = wsL[2048 + (q+1)*1024 + i];
            }
            const int cur = (q & 1) ? WT1 : WT0;
            h8 b10 = ldh(&S[cur +       (llo   )*16 + boff]);
            h8 b11 = ldh(&S[cur +       (llo+16)*16 + boff]);
            h8 b20 = ldh(&S[cur + 512 + (llo   )*16 + boff]);
            h8 b21 = ldh(&S[cur + 512 + (llo+16)*16 + boff]);
            f32x4 ha[4][2];
            #pragma unroll
            for (int j = 0; j < 4; ++j) {
                h8 a = ldh(&S[XN + (wid*64 + j*16 + llo)*16 + boff]);
                ha[j][0] = __builtin_amdgcn_mfma_f32_16x16x32_f16(a, b10, zz, 0,0,0);
                ha[j][1] = __builtin_amdgcn_mfma_f32_16x16x32_f16(a, b11, zz, 0,0,0);
            }
            #pragma unroll
            for (int j = 0; j < 4; ++j) {
                int rowb = wid*64 + j*16 + lhi*4;
                #pragma unroll
                for (int rg = 0; rg < 4; ++rg)
                    S[KPP + (rowb+rg)*16 + llo] = pkh(gelu_f(ha[j][0][rg]), gelu_f(ha[j][1][rg]));
            }
            #pragma unroll
            for (int j = 0; j < 4; ++j) {
                h8 ah = ldh(&S[KPP + (wid*64 + j*16 + llo)*16 + boff]);
                cf[j][0] = __builtin_amdgcn_mfma_f32_16x16x32_f16(ah, b20, cf[j][0], 0,0,0);
                cf[j][1] = __builtin_amdgcn_mfma_f32_16x16x32_f16(ah, b21, cf[j][1], 0,0,0);
            }
            if (q < 3) __syncthreads();                  // B5/B6/B7
        }
        #pragma unroll
        for (int j = 0; j < 4; ++j) {
            int rowb = wid*64 + j*16 + lhi*4;
            #pragma unroll
            for (int rg = 0; rg < 4; ++rg)
                S[VPP + (rowb+rg)*16 + llo] = pkh(cf[j][0][rg], cf[j][1][rg]);
        }
        #pragma unroll
        for (int g = 0; g < 4; ++g) {                    // residual (own row)
            uint4 v = *(const uint4*)&S[VPP + tid*16 + 4*g];
            X[4*g+0] += lo16(v.x); X[16+4*g+0] += hi16(v.x);
            X[4*g+1] += lo16(v.y); X[16+4*g+1] += hi16(v.y);
            X[4*g+2] += lo16(v.z); X[16+4*g+2] += hi16(v.z);
            X[4*g+3] += lo16(v.w); X[16+4*g+3] += hi16(v.w);
        }
    }

    // ---- final LN + weight-tied logits ----
    ln_write(X, &S[XN + tid*16]);
    for (int i = tid; i < 256; i += ROWS) S[WT0 + i] = ws[12288 + i];
    __syncthreads();                                     // B8
    {
        h8 bt = ldh(&S[WT0 + llo*16 + boff]);
        f32x4 lg[4];
        #pragma unroll
        for (int j = 0; j < 4; ++j) {
            h8 a = ldh(&S[XN + (wid*64 + j*16 + llo)*16 + boff]);
            lg[j] = __builtin_amdgcn_mfma_f32_16x16x32_f16(a, bt, zz, 0,0,0);
        }
        #pragma unroll
        for (int j = 0; j < 4; ++j) {
            int rowb = wid*64 + j*16 + lhi*4;
            #pragma unroll
            for (int rg = 0; rg < 4; ++rg)
                S[KPP + (rowb+rg)*16 + llo] = __float_as_uint(lg[j][rg]);
        }
    }
    __syncthreads();                                     // B9
    #pragma unroll
    for (int i = 0; i < VOC; ++i) {                      // coalesced f32 out
        int flat = tid + ROWS * i;
        int row = flat / VOC, col = flat % VOC;
        out[gbase*VOC + flat] = __uint_as_float(S[KPP + row*16 + col]);
    }
}

extern "C" void kernel_launch(void* const* d_in, const int* in_sizes, int n_in,
                              void* d_out, int out_size, void* d_ws, size_t ws_size,
                              hipStream_t stream) {
    const int*   toks = (const int*)  d_in[0];
    const float* temb = (const float*)d_in[1];
    const float* pemb = (const float*)d_in[2];
    const float* wq   = (const float*)d_in[3];
    const float* wk   = (const float*)d_in[4];
    const float* wv   = (const float*)d_in[5];
    const float* wo   = (const float*)d_in[6];
    const float* w1   = (const float*)d_in[7];
    const float* w2   = (const float*)d_in[8];
    unsigned int* ws  = (unsigned int*)d_ws;             // 12544 u32 = 50 KB used
    float* out = (float*)d_out;
    const int batch = in_sizes[0] / SEQ;                 // 131072
    const int nblk  = (batch * SEQ) / ROWS;              // 4096

    prep<<<dim3(25), dim3(64), 0, stream>>>(temb, wq, wk, wv, wo, w1, w2, ws);
    tf_mfma<<<dim3(nblk), dim3(ROWS), 0, stream>>>(toks, temb, pemb, ws, out);
}

// Round 4
// 245.010 us; speedup vs baseline: 5.6561x; 1.0076x over previous
//
#include <hip/hip_runtime.h>

#define SEQ 6
#define ROWS 192                 // 3 waves; thread = one (elem,seq) row
#define NL 2
#define VOC 15

typedef __attribute__((ext_vector_type(8))) _Float16 h8;
typedef __attribute__((ext_vector_type(2))) _Float16 h2;
typedef __attribute__((ext_vector_type(4))) float    f32x4;

// LDS pools (u32 words), row stride 16, XOR-swizzled 16B groups.
// Total 8704 u32 = 34 KB.
#define XN   0        // 192*16: Xn -> Q -> O -> Xn2   (own-row / own-wave)
#define KV   3072     // 192*16: K -> V -> OWo -> H -> FFN2 -> logits
#define WT   6144     // 2560: slotA 0..1023, slotB 1024..2047, Wo/TE 2048..2559
#define SMEM_U32 8704

// ws layout (u32): per layer L at L*6144: Wq 0, Wk 512, Wv 1024, Wo 1536,
// quarter q: 2048+q*1024 (W1q at +0, W2q at +512). TE at 12288 (256).

__device__ __forceinline__ unsigned int pkh(float a, float b) {
    auto h = __builtin_amdgcn_cvt_pkrtz(a, b);       // v_cvt_pkrtz_f16_f32
    return __builtin_bit_cast(unsigned int, h);
}
__device__ __forceinline__ float lo16(unsigned int u) {
    h2 h = __builtin_bit_cast(h2, u); return (float)h.x;
}
__device__ __forceinline__ float hi16(unsigned int u) {
    h2 h = __builtin_bit_cast(h2, u); return (float)h.y;
}
__device__ __forceinline__ h8 ldh(const unsigned int* p) {
    uint4 u = *(const uint4*)p;
    return __builtin_bit_cast(h8, u);
}
#if __has_builtin(__builtin_amdgcn_fdot2)
__device__ __forceinline__ float dot2acc(unsigned int a, unsigned int b, float c) {
    return __builtin_amdgcn_fdot2(__builtin_bit_cast(h2, a), __builtin_bit_cast(h2, b), c, false);
}
#else
__device__ __forceinline__ float dot2acc(unsigned int a, unsigned int b, float c) {
    return fmaf(hi16(a), hi16(b), fmaf(lo16(a), lo16(b), c));
}
#endif
__device__ __forceinline__ float gelu_f(float x) {   // sigmoid-form tanh-GELU
    float t = x * x;
    float v = x * fmaf(0.0713548162726f, t, 1.5957691216057308f);
    return x * __builtin_amdgcn_rcpf(1.0f + __expf(-v));
}
// head permutation: permuted col p -> original col (sigma pairs head-local)
__device__ __forceinline__ int permc(int p) {
    int h = (p & 15) >> 2, j = p & 3, hi = p >> 4;
    return 8*h + 2*j + hi;
}
// swizzled 16B-group word offset within a pool row
__device__ __forceinline__ int swg(int row, int g) {
    return ((g ^ ((row >> 1) & 3)) << 2);
}
// LN(X) -> sigma-packed f16 row, swizzled
__device__ __forceinline__ void ln_write(const float* X, unsigned int* base, int row) {
    float mu = 0.f;
    #pragma unroll
    for (int c = 0; c < 32; ++c) mu += X[c];
    mu *= 0.03125f;
    float var = 0.f;
    #pragma unroll
    for (int c = 0; c < 32; ++c) { float d = X[c] - mu; var += d * d; }
    var *= 0.03125f;
    float rs = rsqrtf(var + 1e-5f), b = -mu * rs;
    unsigned int* rp = base + row * 16;
    const int k = (row >> 1) & 3;
    #pragma unroll
    for (int g = 0; g < 4; ++g) {
        uint4 w;
        w.x = pkh(fmaf(X[4*g+0], rs, b), fmaf(X[16+4*g+0], rs, b));
        w.y = pkh(fmaf(X[4*g+1], rs, b), fmaf(X[16+4*g+1], rs, b));
        w.z = pkh(fmaf(X[4*g+2], rs, b), fmaf(X[16+4*g+2], rs, b));
        w.w = pkh(fmaf(X[4*g+3], rs, b), fmaf(X[16+4*g+3], rs, b));
        *(uint4*)&rp[(g ^ k) << 2] = w;
    }
}

// ---- prep: pre-pack all weights (f16, transposed, head-permuted) into ws ----
__global__ __launch_bounds__(64) void prep(
    const float* __restrict__ temb, const float* __restrict__ wq,
    const float* __restrict__ wk, const float* __restrict__ wv,
    const float* __restrict__ wo, const float* __restrict__ w1,
    const float* __restrict__ w2, unsigned int* __restrict__ ws)
{
    const int part = blockIdx.x;          // 0..24
    const int t = threadIdx.x;
    if (part == 24) {                     // TE tile
        for (int i = t; i < 256; i += 64) {
            int c = i >> 4, w = i & 15;
            ws[12288 + i] = (c < VOC) ? pkh(temb[c*32 + w], temb[c*32 + w + 16]) : 0u;
        }
        return;
    }
    const int L = part / 12, m = part % 12;
    unsigned int* o = ws + L * 6144;
    for (int i = t; i < 512; i += 64) {
        int c = i >> 4, w = i & 15;
        if (m < 3) {
            const float* M = (m == 0 ? wq : (m == 1 ? wk : wv)) + L*1024;
            int pc = permc(c);
            o[m*512 + i] = pkh(M[w*32 + pc], M[(w+16)*32 + pc]);
        } else if (m == 3) {
            const float* M = wo + L*1024;
            o[1536 + i] = pkh(M[permc(w)*32 + c], M[permc(w+16)*32 + c]);
        } else if (m < 8) {
            int q = m - 4;
            const float* M = w1 + L*4096;
            o[2048 + q*1024 + i] = pkh(M[w*128 + 32*q + c], M[(w+16)*128 + 32*q + c]);
        } else {
            int q = m - 8;
            const float* M = w2 + L*4096;
            o[2048 + q*1024 + 512 + i] = pkh(M[(32*q+w)*32 + c], M[(32*q+16+w)*32 + c]);
        }
    }
}

__global__ __launch_bounds__(ROWS, 2)
void tf_mfma(const int* __restrict__ toks, const float* __restrict__ temb,
             const float* __restrict__ pemb, const unsigned int* __restrict__ ws,
             float* __restrict__ out)
{
    __shared__ unsigned int S[SMEM_U32];
    const int tid  = threadIdx.x;
    const int lane = tid & 63;
    const int wid  = tid >> 6;
    const int llo  = lane & 15, lhi = lane >> 4;
    const int boff = 4 * lhi;
    const int s    = tid % SEQ;
    const int rb   = tid - s;
    const int myk  = (tid >> 1) & 3;                 // own-row swizzle key
    const long long gbase = (long long)blockIdx.x * ROWS;
    const f32x4 zz = {0.f, 0.f, 0.f, 0.f};

    float X[32];
    {
        const int tok = toks[gbase + tid];
        #pragma unroll
        for (int g = 0; g < 8; ++g) {
            float4 a = *(const float4*)&temb[tok*32 + 4*g];
            float4 b = *(const float4*)&pemb[s*32 + 4*g];
            X[4*g+0] = a.x + b.x; X[4*g+1] = a.y + b.y;
            X[4*g+2] = a.z + b.z; X[4*g+3] = a.w + b.w;
        }
    }

    #pragma unroll 1
    for (int L = 0; L < NL; ++L) {
        const unsigned int* wsL = ws + L * 6144;

        __syncthreads();                             // B0: WT (q3) free
        ln_write(X, &S[XN], tid);                    // Xn (own row)
        for (int i = tid; i < 1536; i += ROWS) S[WT + i] = wsL[i];   // Wq,Wk,Wv
        __syncthreads();                             // B1

        f32x4 vf[4][2];
        uint4 q4[4];
        {
            h8 bq0 = ldh(&S[WT +        (llo   )*16 + boff]);
            h8 bq1 = ldh(&S[WT +        (llo+16)*16 + boff]);
            h8 bk0 = ldh(&S[WT +  512 + (llo   )*16 + boff]);
            h8 bk1 = ldh(&S[WT +  512 + (llo+16)*16 + boff]);
            h8 bv0 = ldh(&S[WT + 1024 + (llo   )*16 + boff]);
            h8 bv1 = ldh(&S[WT + 1024 + (llo+16)*16 + boff]);
            h8 aa[4];
            #pragma unroll
            for (int j = 0; j < 4; ++j) {
                int rowa = wid*64 + j*16 + llo;
                aa[j] = ldh(&S[XN + rowa*16 + swg(rowa, lhi)]);
            }
            #pragma unroll
            for (int j = 0; j < 4; ++j) {            // K -> KV pool
                f32x4 k0 = __builtin_amdgcn_mfma_f32_16x16x32_f16(aa[j], bk0, zz, 0,0,0);
                f32x4 k1 = __builtin_amdgcn_mfma_f32_16x16x32_f16(aa[j], bk1, zz, 0,0,0);
                int rowb = wid*64 + j*16 + lhi*4;
                #pragma unroll
                for (int rg = 0; rg < 4; ++rg) {
                    int row = rowb + rg;
                    S[KV + row*16 + swg(row, llo >> 2) + (llo & 3)] = pkh(k0[rg], k1[rg]);
                }
            }
            #pragma unroll
            for (int j = 0; j < 4; ++j) {            // Q -> XN pool (over Xn)
                f32x4 q0 = __builtin_amdgcn_mfma_f32_16x16x32_f16(aa[j], bq0, zz, 0,0,0);
                f32x4 q1 = __builtin_amdgcn_mfma_f32_16x16x32_f16(aa[j], bq1, zz, 0,0,0);
                int rowb = wid*64 + j*16 + lhi*4;
                #pragma unroll
                for (int rg = 0; rg < 4; ++rg) {
                    int row = rowb + rg;
                    S[XN + row*16 + swg(row, llo >> 2) + (llo & 3)] = pkh(q0[rg], q1[rg]);
                }
            }
            #pragma unroll
            for (int j = 0; j < 4; ++j) {            // V stays in registers
                vf[j][0] = __builtin_amdgcn_mfma_f32_16x16x32_f16(aa[j], bv0, zz, 0,0,0);
                vf[j][1] = __builtin_amdgcn_mfma_f32_16x16x32_f16(aa[j], bv1, zz, 0,0,0);
            }
            #pragma unroll
            for (int h = 0; h < 4; ++h)              // own-row Q (own-wave rows)
                q4[h] = *(const uint4*)&S[XN + tid*16 + ((h ^ myk) << 2)];
        }
        __syncthreads();                             // B2: K visible, QKV tiles dead

        // ---- stage Wo+q0+q1 (overlaps scores) + scores + softmax ----
        float p[4][SEQ], rd[4];
        {
            for (int i = tid; i < 512;  i += ROWS) S[WT + 2048 + i] = wsL[1536 + i];
            for (int i = tid; i < 2048; i += ROWS) S[WT + i] = wsL[2048 + i];  // q0,q1
            float den[4] = {0.f, 0.f, 0.f, 0.f};
            #pragma unroll
            for (int t = 0; t < SEQ; ++t) {
                int krow = rb + t;
                const unsigned int* kr = &S[KV + krow*16];
                int kk4 = (krow >> 1) & 3;
                float msk = (t <= s) ? 0.f : -1e30f;
                #pragma unroll
                for (int h = 0; h < 4; ++h) {
                    uint4 kk = *(const uint4*)&kr[(h ^ kk4) << 2];
                    float d = dot2acc(q4[h].x, kk.x, 0.f);
                    d = dot2acc(q4[h].y, kk.y, d);
                    d = dot2acc(q4[h].z, kk.z, d);
                    d = dot2acc(q4[h].w, kk.w, d);
                    float e = __expf(fmaf(d, 0.35355339059327373f, msk));
                    p[h][t] = e; den[h] += e;
                }
            }
            #pragma unroll
            for (int h = 0; h < 4; ++h) rd[h] = __builtin_amdgcn_rcpf(den[h]);
        }
        __syncthreads();                             // B3: all K reads done
        #pragma unroll
        for (int j = 0; j < 4; ++j) {                // V -> KV pool (over K)
            int rowb = wid*64 + j*16 + lhi*4;
            #pragma unroll
            for (int rg = 0; rg < 4; ++rg) {
                int row = rowb + rg;
                S[KV + row*16 + swg(row, llo >> 2) + (llo & 3)] = pkh(vf[j][0][rg], vf[j][1][rg]);
            }
        }
        __syncthreads();                             // B4: V visible

        // ---- PV (packed f16 fma) -> O -> XN own row ----
        {
            h2 O[16];
            #pragma unroll
            for (int w = 0; w < 16; ++w) O[w] = __builtin_bit_cast(h2, 0u);
            #pragma unroll
            for (int t = 0; t < SEQ; ++t) {
                int vrow = rb + t;
                const unsigned int* vr = &S[KV + vrow*16];
                int vk4 = (vrow >> 1) & 3;
                #pragma unroll
                for (int h = 0; h < 4; ++h) {
                    float wg = p[h][t] * rd[h];
                    h2 wg2 = __builtin_bit_cast(h2, pkh(wg, wg));
                    uint4 vv = *(const uint4*)&vr[(h ^ vk4) << 2];
                    O[4*h+0] += __builtin_bit_cast(h2, vv.x) * wg2;
                    O[4*h+1] += __builtin_bit_cast(h2, vv.y) * wg2;
                    O[4*h+2] += __builtin_bit_cast(h2, vv.z) * wg2;
                    O[4*h+3] += __builtin_bit_cast(h2, vv.w) * wg2;
                }
            }
            #pragma unroll
            for (int g = 0; g < 4; ++g) {
                uint4 w;
                w.x = __builtin_bit_cast(unsigned int, O[4*g+0]);
                w.y = __builtin_bit_cast(unsigned int, O[4*g+1]);
                w.z = __builtin_bit_cast(unsigned int, O[4*g+2]);
                w.w = __builtin_bit_cast(unsigned int, O[4*g+3]);
                *(uint4*)&S[XN + tid*16 + ((g ^ myk) << 2)] = w;
            }
        }
        __syncthreads();                             // B5: O rows visible

        // ---- O.Wo (MFMA) -> KV, residual, LN2 ----
        {
            h8 bo0 = ldh(&S[WT + 2048 + (llo   )*16 + boff]);
            h8 bo1 = ldh(&S[WT + 2048 + (llo+16)*16 + boff]);
            #pragma unroll
            for (int j = 0; j < 4; ++j) {
                int rowa = wid*64 + j*16 + llo;
                h8 a = ldh(&S[XN + rowa*16 + swg(rowa, lhi)]);
                f32x4 o0 = __builtin_amdgcn_mfma_f32_16x16x32_f16(a, bo0, zz, 0,0,0);
                f32x4 o1 = __builtin_amdgcn_mfma_f32_16x16x32_f16(a, bo1, zz, 0,0,0);
                int rowb = wid*64 + j*16 + lhi*4;
                #pragma unroll
                for (int rg = 0; rg < 4; ++rg) {
                    int row = rowb + rg;
                    S[KV + row*16 + swg(row, llo >> 2) + (llo & 3)] = pkh(o0[rg], o1[rg]);
                }
            }
        }
        #pragma unroll
        for (int g = 0; g < 4; ++g) {                // residual (own-wave rows)
            uint4 v = *(const uint4*)&S[KV + tid*16 + ((g ^ myk) << 2)];
            X[4*g+0] += lo16(v.x); X[16+4*g+0] += hi16(v.x);
            X[4*g+1] += lo16(v.y); X[16+4*g+1] += hi16(v.y);
            X[4*g+2] += lo16(v.z); X[16+4*g+2] += hi16(v.z);
            X[4*g+3] += lo16(v.w); X[16+4*g+3] += hi16(v.w);
        }
        ln_write(X, &S[XN], tid);                    // Xn2 (own row)

        // ---- FFN: 4 quarters, slotA/slotB ping-pong, FFN2 accumulates ----
        f32x4 cf[4][2];
        #pragma unroll
        for (int j = 0; j < 4; ++j) { cf[j][0] = zz; cf[j][1] = zz; }
        #pragma unroll
        for (int q = 0; q < 4; ++q) {
            const int cur = (q & 1) ? (WT + 1024) : WT;
            if (q == 1 || q == 2) {                  // stage q+2 into dead slot
                const int dst = WT + (((q + 1) & 1) ? 1024 : 0);
                for (int i = tid; i < 1024; i += ROWS) S[dst + i] = wsL[2048 + (q+1)*1024 + i];
            }
            h8 b10 = ldh(&S[cur +       (llo   )*16 + boff]);
            h8 b11 = ldh(&S[cur +       (llo+16)*16 + boff]);
            h8 b20 = ldh(&S[cur + 512 + (llo   )*16 + boff]);
            h8 b21 = ldh(&S[cur + 512 + (llo+16)*16 + boff]);
            #pragma unroll
            for (int j = 0; j < 4; ++j) {
                int rowa = wid*64 + j*16 + llo;
                h8 a = ldh(&S[XN + rowa*16 + swg(rowa, lhi)]);
                f32x4 h0 = __builtin_amdgcn_mfma_f32_16x16x32_f16(a, b10, zz, 0,0,0);
                f32x4 h1 = __builtin_amdgcn_mfma_f32_16x16x32_f16(a, b11, zz, 0,0,0);
                int rowb = wid*64 + j*16 + lhi*4;
                #pragma unroll
                for (int rg = 0; rg < 4; ++rg) {
                    int row = rowb + rg;
                    S[KV + row*16 + swg(row, llo >> 2) + (llo & 3)] =
                        pkh(gelu_f(h0[rg]), gelu_f(h1[rg]));
                }
            }
            #pragma unroll
            for (int j = 0; j < 4; ++j) {            // FFN2 (own-wave H rows)
                int rowa = wid*64 + j*16 + llo;
                h8 ah = ldh(&S[KV + rowa*16 + swg(rowa, lhi)]);
                cf[j][0] = __builtin_amdgcn_mfma_f32_16x16x32_f16(ah, b20, cf[j][0], 0,0,0);
                cf[j][1] = __builtin_amdgcn_mfma_f32_16x16x32_f16(ah, b21, cf[j][1], 0,0,0);
            }
            if (q < 3) __syncthreads();              // Bq
        }
        #pragma unroll
        for (int j = 0; j < 4; ++j) {                // FFN2 out -> KV (own-wave)
            int rowb = wid*64 + j*16 + lhi*4;
            #pragma unroll
            for (int rg = 0; rg < 4; ++rg) {
                int row = rowb + rg;
                S[KV + row*16 + swg(row, llo >> 2) + (llo & 3)] = pkh(cf[j][0][rg], cf[j][1][rg]);
            }
        }
        #pragma unroll
        for (int g = 0; g < 4; ++g) {                // residual (own-wave rows)
            uint4 v = *(const uint4*)&S[KV + tid*16 + ((g ^ myk) << 2)];
            X[4*g+0] += lo16(v.x); X[16+4*g+0] += hi16(v.x);
            X[4*g+1] += lo16(v.y); X[16+4*g+1] += hi16(v.y);
            X[4*g+2] += lo16(v.z); X[16+4*g+2] += hi16(v.z);
            X[4*g+3] += lo16(v.w); X[16+4*g+3] += hi16(v.w);
        }
    }

    // ---- final LN + weight-tied logits ----
    __syncthreads();                                 // WT (q3) free
    ln_write(X, &S[XN], tid);
    for (int i = tid; i < 256; i += ROWS) S[WT + i] = ws[12288 + i];
    __syncthreads();
    {
        h8 bt = ldh(&S[WT + llo*16 + boff]);
        #pragma unroll
        for (int j = 0; j < 4; ++j) {
            int rowa = wid*64 + j*16 + llo;
            h8 a = ldh(&S[XN + rowa*16 + swg(rowa, lhi)]);
            f32x4 lg = __builtin_amdgcn_mfma_f32_16x16x32_f16(a, bt, zz, 0,0,0);
            int rowb = wid*64 + j*16 + lhi*4;
            #pragma unroll
            for (int rg = 0; rg < 4; ++rg) {
                int row = rowb + rg;
                S[KV + row*16 + swg(row, llo >> 2) + (llo & 3)] = __float_as_uint(lg[rg]);
            }
        }
    }
    __syncthreads();
    #pragma unroll
    for (int i = 0; i < VOC; ++i) {                  // coalesced f32 out
        int flat = tid + ROWS * i;
        int row = flat / VOC, col = flat % VOC;
        out[gbase*VOC + flat] =
            __uint_as_float(S[KV + row*16 + (((col >> 2) ^ ((row >> 1) & 3)) << 2) + (col & 3)]);
    }
}

extern "C" void kernel_launch(void* const* d_in, const int* in_sizes, int n_in,
                              void* d_out, int out_size, void* d_ws, size_t ws_size,
                              hipStream_t stream) {
    const int*   toks = (const int*)  d_in[0];
    const float* temb = (const float*)d_in[1];
    const float* pemb = (const float*)d_in[2];
    const float* wq   = (const float*)d_in[3];
    const float* wk   = (const float*)d_in[4];
    const float* wv   = (const float*)d_in[5];
    const float* wo   = (const float*)d_in[6];
    const float* w1   = (const float*)d_in[7];
    const float* w2   = (const float*)d_in[8];
    unsigned int* ws  = (unsigned int*)d_ws;         // 12544 u32 = 50 KB used
    float* out = (float*)d_out;
    const int batch = in_sizes[0] / SEQ;             // 131072
    const int nblk  = (batch * SEQ) / ROWS;          // 4096

    prep<<<dim3(25), dim3(64), 0, stream>>>(temb, wq, wk, wv, wo, w1, w2, ws);
    tf_mfma<<<dim3(nblk), dim3(ROWS), 0, stream>>>(toks, temb, pemb, ws, out);
}

// Round 5
// 221.776 us; speedup vs baseline: 6.2486x; 1.1048x over previous
//
#include <hip/hip_runtime.h>

#define SEQ 6
#define ROWS 384                 // 6 waves; thread = one (elem,seq) row; 64 elems/block
#define NL 2
#define VOC 15

typedef __attribute__((ext_vector_type(8))) _Float16 h8;
typedef __attribute__((ext_vector_type(2))) _Float16 h2;
typedef __attribute__((ext_vector_type(4))) float    f32x4;

// LDS pools (u32 words), row stride 16, XOR-swizzled 16B groups. 18432 u32 = 72 KB.
#define XN   0        // 384*16: Xn -> Q -> O -> OWo -> Xn2  (own-row / own-wave only)
#define KP   6144     // 384*16: K -> H(quarter) -> FFN2 out -> logits f32
#define VP   12288    // 384*16: V
#define SMEM_U32 18432

// ws layout (u32): per layer L at L*6144: Wq 0, Wk 512, Wv 1024, Wo 1536,
// quarter q: 2048+q*1024 (W1q at +0, W2q at +512). TE at 12288 (256).

__device__ __forceinline__ unsigned int pkh(float a, float b) {
    auto h = __builtin_amdgcn_cvt_pkrtz(a, b);       // v_cvt_pkrtz_f16_f32
    return __builtin_bit_cast(unsigned int, h);
}
__device__ __forceinline__ float lo16(unsigned int u) {
    h2 h = __builtin_bit_cast(h2, u); return (float)h.x;
}
__device__ __forceinline__ float hi16(unsigned int u) {
    h2 h = __builtin_bit_cast(h2, u); return (float)h.y;
}
__device__ __forceinline__ h8 ldh(const unsigned int* p) {
    uint4 u = *(const uint4*)p;
    return __builtin_bit_cast(h8, u);
}
#if __has_builtin(__builtin_amdgcn_fdot2)
__device__ __forceinline__ float dot2acc(unsigned int a, unsigned int b, float c) {
    return __builtin_amdgcn_fdot2(__builtin_bit_cast(h2, a), __builtin_bit_cast(h2, b), c, false);
}
#else
__device__ __forceinline__ float dot2acc(unsigned int a, unsigned int b, float c) {
    return fmaf(hi16(a), hi16(b), fmaf(lo16(a), lo16(b), c));
}
#endif
__device__ __forceinline__ float gelu_f(float x) {   // sigmoid-form tanh-GELU
    float t = x * x;
    float v = x * fmaf(0.0713548162726f, t, 1.5957691216057308f);
    return x * __builtin_amdgcn_rcpf(1.0f + __expf(-v));
}
// head permutation: permuted col p -> original col (sigma pairs head-local)
__device__ __forceinline__ int permc(int p) {
    int h = (p & 15) >> 2, j = p & 3, hi = p >> 4;
    return 8*h + 2*j + hi;
}
// swizzled 16B-group word offset within a pool row
__device__ __forceinline__ int swg(int row, int g) {
    return ((g ^ ((row >> 1) & 3)) << 2);
}
// LN(X) -> sigma-packed f16 row, swizzled
__device__ __forceinline__ void ln_write(const float* X, unsigned int* base, int row) {
    float mu = 0.f;
    #pragma unroll
    for (int c = 0; c < 32; ++c) mu += X[c];
    mu *= 0.03125f;
    float var = 0.f;
    #pragma unroll
    for (int c = 0; c < 32; ++c) { float d = X[c] - mu; var += d * d; }
    var *= 0.03125f;
    float rs = rsqrtf(var + 1e-5f), b = -mu * rs;
    unsigned int* rp = base + row * 16;
    const int k = (row >> 1) & 3;
    #pragma unroll
    for (int g = 0; g < 4; ++g) {
        uint4 w;
        w.x = pkh(fmaf(X[4*g+0], rs, b), fmaf(X[16+4*g+0], rs, b));
        w.y = pkh(fmaf(X[4*g+1], rs, b), fmaf(X[16+4*g+1], rs, b));
        w.z = pkh(fmaf(X[4*g+2], rs, b), fmaf(X[16+4*g+2], rs, b));
        w.w = pkh(fmaf(X[4*g+3], rs, b), fmaf(X[16+4*g+3], rs, b));
        *(uint4*)&rp[(g ^ k) << 2] = w;
    }
}

// ---- prep: pre-pack all weights (f16, transposed, head-permuted) into ws ----
__global__ __launch_bounds__(64) void prep(
    const float* __restrict__ temb, const float* __restrict__ wq,
    const float* __restrict__ wk, const float* __restrict__ wv,
    const float* __restrict__ wo, const float* __restrict__ w1,
    const float* __restrict__ w2, unsigned int* __restrict__ ws)
{
    const int part = blockIdx.x;          // 0..24
    const int t = threadIdx.x;
    if (part == 24) {                     // TE tile
        for (int i = t; i < 256; i += 64) {
            int c = i >> 4, w = i & 15;
            ws[12288 + i] = (c < VOC) ? pkh(temb[c*32 + w], temb[c*32 + w + 16]) : 0u;
        }
        return;
    }
    const int L = part / 12, m = part % 12;
    unsigned int* o = ws + L * 6144;
    for (int i = t; i < 512; i += 64) {
        int c = i >> 4, w = i & 15;
        if (m < 3) {
            const float* M = (m == 0 ? wq : (m == 1 ? wk : wv)) + L*1024;
            int pc = permc(c);
            o[m*512 + i] = pkh(M[w*32 + pc], M[(w+16)*32 + pc]);
        } else if (m == 3) {
            const float* M = wo + L*1024;
            o[1536 + i] = pkh(M[permc(w)*32 + c], M[permc(w+16)*32 + c]);
        } else if (m < 8) {
            int q = m - 4;
            const float* M = w1 + L*4096;
            o[2048 + q*1024 + i] = pkh(M[w*128 + 32*q + c], M[(w+16)*128 + 32*q + c]);
        } else {
            int q = m - 8;
            const float* M = w2 + L*4096;
            o[2048 + q*1024 + 512 + i] = pkh(M[(32*q+w)*32 + c], M[(32*q+16+w)*32 + c]);
        }
    }
}

__global__ __launch_bounds__(ROWS, 3)
void tf_mfma(const int* __restrict__ toks, const float* __restrict__ temb,
             const float* __restrict__ pemb, const unsigned int* __restrict__ ws,
             float* __restrict__ out)
{
    __shared__ unsigned int S[SMEM_U32];
    const int tid  = threadIdx.x;
    const int lane = tid & 63;
    const int wid  = tid >> 6;
    const int llo  = lane & 15, lhi = lane >> 4;
    const int boff = 4 * lhi;
    const int s    = tid % SEQ;
    const int rb   = tid - s;
    const int myk  = (tid >> 1) & 3;                 // own-row swizzle key
    const long long gbase = (long long)blockIdx.x * ROWS;
    const f32x4 zz = {0.f, 0.f, 0.f, 0.f};

    float X[32];
    {
        const int tok = toks[gbase + tid];
        #pragma unroll
        for (int g = 0; g < 8; ++g) {
            float4 a = *(const float4*)&temb[tok*32 + 4*g];
            float4 b = *(const float4*)&pemb[s*32 + 4*g];
            X[4*g+0] = a.x + b.x; X[4*g+1] = a.y + b.y;
            X[4*g+2] = a.z + b.z; X[4*g+3] = a.w + b.w;
        }
    }

    #pragma unroll 1
    for (int L = 0; L < NL; ++L) {
        const unsigned int* wsL = ws + L * 6144;

        ln_write(X, &S[XN], tid);                    // Xn (own row; own-wave readers)

        // ---- QKV MFMA: B-frags direct from global (L1/L2-resident) ----
        uint4 q4[4];
        {
            h8 bq0 = ldh(wsL +          llo    *16 + boff);
            h8 bq1 = ldh(wsL +         (llo+16)*16 + boff);
            h8 bk0 = ldh(wsL +  512 +   llo    *16 + boff);
            h8 bk1 = ldh(wsL +  512 +  (llo+16)*16 + boff);
            h8 bv0 = ldh(wsL + 1024 +   llo    *16 + boff);
            h8 bv1 = ldh(wsL + 1024 +  (llo+16)*16 + boff);
            h8 aa[4];
            #pragma unroll
            for (int j = 0; j < 4; ++j) {
                int rowa = wid*64 + j*16 + llo;
                aa[j] = ldh(&S[XN + rowa*16 + swg(rowa, lhi)]);
            }
            #pragma unroll
            for (int j = 0; j < 4; ++j) {            // K -> KP (own-wave rows)
                f32x4 k0 = __builtin_amdgcn_mfma_f32_16x16x32_f16(aa[j], bk0, zz, 0,0,0);
                f32x4 k1 = __builtin_amdgcn_mfma_f32_16x16x32_f16(aa[j], bk1, zz, 0,0,0);
                int rowb = wid*64 + j*16 + lhi*4;
                #pragma unroll
                for (int rg = 0; rg < 4; ++rg) {
                    int row = rowb + rg;
                    S[KP + row*16 + swg(row, llo >> 2) + (llo & 3)] = pkh(k0[rg], k1[rg]);
                }
            }
            #pragma unroll
            for (int j = 0; j < 4; ++j) {            // V -> VP
                f32x4 v0 = __builtin_amdgcn_mfma_f32_16x16x32_f16(aa[j], bv0, zz, 0,0,0);
                f32x4 v1 = __builtin_amdgcn_mfma_f32_16x16x32_f16(aa[j], bv1, zz, 0,0,0);
                int rowb = wid*64 + j*16 + lhi*4;
                #pragma unroll
                for (int rg = 0; rg < 4; ++rg) {
                    int row = rowb + rg;
                    S[VP + row*16 + swg(row, llo >> 2) + (llo & 3)] = pkh(v0[rg], v1[rg]);
                }
            }
            #pragma unroll
            for (int j = 0; j < 4; ++j) {            // Q -> XN (over Xn)
                f32x4 q0 = __builtin_amdgcn_mfma_f32_16x16x32_f16(aa[j], bq0, zz, 0,0,0);
                f32x4 q1 = __builtin_amdgcn_mfma_f32_16x16x32_f16(aa[j], bq1, zz, 0,0,0);
                int rowb = wid*64 + j*16 + lhi*4;
                #pragma unroll
                for (int rg = 0; rg < 4; ++rg) {
                    int row = rowb + rg;
                    S[XN + row*16 + swg(row, llo >> 2) + (llo & 3)] = pkh(q0[rg], q1[rg]);
                }
            }
            #pragma unroll
            for (int h = 0; h < 4; ++h)              // own-row Q (intra-wave via lgkmcnt)
                q4[h] = *(const uint4*)&S[XN + tid*16 + ((h ^ myk) << 2)];
        }
        __syncthreads();                             // BK: K,V published (cross-wave edge elems)

        // ---- scores + softmax (no max-sub; |s| small) ----
        float p[4][SEQ], rd[4];
        {
            float den[4] = {0.f, 0.f, 0.f, 0.f};
            #pragma unroll
            for (int t = 0; t < SEQ; ++t) {
                int krow = rb + t;
                const unsigned int* kr = &S[KP + krow*16];
                int kk4 = (krow >> 1) & 3;
                float msk = (t <= s) ? 0.f : -1e30f;
                #pragma unroll
                for (int h = 0; h < 4; ++h) {
                    uint4 kk = *(const uint4*)&kr[(h ^ kk4) << 2];
                    float d = dot2acc(q4[h].x, kk.x, 0.f);
                    d = dot2acc(q4[h].y, kk.y, d);
                    d = dot2acc(q4[h].z, kk.z, d);
                    d = dot2acc(q4[h].w, kk.w, d);
                    float e = __expf(fmaf(d, 0.35355339059327373f, msk));
                    p[h][t] = e; den[h] += e;
                }
            }
            #pragma unroll
            for (int h = 0; h < 4; ++h) rd[h] = __builtin_amdgcn_rcpf(den[h]);
        }
        // ---- PV (packed f16 fma) -> O -> XN own row (over Q) ----
        {
            h2 O[16];
            #pragma unroll
            for (int w = 0; w < 16; ++w) O[w] = __builtin_bit_cast(h2, 0u);
            #pragma unroll
            for (int t = 0; t < SEQ; ++t) {
                int vrow = rb + t;
                const unsigned int* vr = &S[VP + vrow*16];
                int vk4 = (vrow >> 1) & 3;
                #pragma unroll
                for (int h = 0; h < 4; ++h) {
                    float wg = p[h][t] * rd[h];
                    h2 wg2 = __builtin_bit_cast(h2, pkh(wg, wg));
                    uint4 vv = *(const uint4*)&vr[(h ^ vk4) << 2];
                    O[4*h+0] += __builtin_bit_cast(h2, vv.x) * wg2;
                    O[4*h+1] += __builtin_bit_cast(h2, vv.y) * wg2;
                    O[4*h+2] += __builtin_bit_cast(h2, vv.z) * wg2;
                    O[4*h+3] += __builtin_bit_cast(h2, vv.w) * wg2;
                }
            }
            #pragma unroll
            for (int g = 0; g < 4; ++g) {
                uint4 w;
                w.x = __builtin_bit_cast(unsigned int, O[4*g+0]);
                w.y = __builtin_bit_cast(unsigned int, O[4*g+1]);
                w.z = __builtin_bit_cast(unsigned int, O[4*g+2]);
                w.w = __builtin_bit_cast(unsigned int, O[4*g+3]);
                *(uint4*)&S[XN + tid*16 + ((g ^ myk) << 2)] = w;
            }
        }
        __syncthreads();                             // BA: all K/V cross-reads done

        // ---- O.Wo (MFMA, B direct-global) -> XN, residual, LN2 ----
        {
            h8 bo0 = ldh(wsL + 1536 +  llo    *16 + boff);
            h8 bo1 = ldh(wsL + 1536 + (llo+16)*16 + boff);
            #pragma unroll
            for (int j = 0; j < 4; ++j) {
                int rowa = wid*64 + j*16 + llo;
                h8 a = ldh(&S[XN + rowa*16 + swg(rowa, lhi)]);
                f32x4 o0 = __builtin_amdgcn_mfma_f32_16x16x32_f16(a, bo0, zz, 0,0,0);
                f32x4 o1 = __builtin_amdgcn_mfma_f32_16x16x32_f16(a, bo1, zz, 0,0,0);
                int rowb = wid*64 + j*16 + lhi*4;
                #pragma unroll
                for (int rg = 0; rg < 4; ++rg) {
                    int row = rowb + rg;
                    S[XN + row*16 + swg(row, llo >> 2) + (llo & 3)] = pkh(o0[rg], o1[rg]);
                }
            }
        }
        #pragma unroll
        for (int g = 0; g < 4; ++g) {                // residual (own row)
            uint4 v = *(const uint4*)&S[XN + tid*16 + ((g ^ myk) << 2)];
            X[4*g+0] += lo16(v.x); X[16+4*g+0] += hi16(v.x);
            X[4*g+1] += lo16(v.y); X[16+4*g+1] += hi16(v.y);
            X[4*g+2] += lo16(v.z); X[16+4*g+2] += hi16(v.z);
            X[4*g+3] += lo16(v.w); X[16+4*g+3] += hi16(v.w);
        }
        ln_write(X, &S[XN], tid);                    // Xn2 (own row)

        // ---- FFN: 4 quarters, weights direct-global, zero barriers ----
        f32x4 cf[4][2];
        #pragma unroll
        for (int j = 0; j < 4; ++j) { cf[j][0] = zz; cf[j][1] = zz; }
        #pragma unroll
        for (int q = 0; q < 4; ++q) {
            const unsigned int* wq4 = wsL + 2048 + q*1024;
            h8 b10 = ldh(wq4 +        llo    *16 + boff);
            h8 b11 = ldh(wq4 +       (llo+16)*16 + boff);
            h8 b20 = ldh(wq4 + 512 +  llo    *16 + boff);
            h8 b21 = ldh(wq4 + 512 + (llo+16)*16 + boff);
            #pragma unroll
            for (int j = 0; j < 4; ++j) {
                int rowa = wid*64 + j*16 + llo;
                h8 a = ldh(&S[XN + rowa*16 + swg(rowa, lhi)]);
                f32x4 h0 = __builtin_amdgcn_mfma_f32_16x16x32_f16(a, b10, zz, 0,0,0);
                f32x4 h1 = __builtin_amdgcn_mfma_f32_16x16x32_f16(a, b11, zz, 0,0,0);
                int rowb = wid*64 + j*16 + lhi*4;
                #pragma unroll
                for (int rg = 0; rg < 4; ++rg) {
                    int row = rowb + rg;
                    S[KP + row*16 + swg(row, llo >> 2) + (llo & 3)] =
                        pkh(gelu_f(h0[rg]), gelu_f(h1[rg]));
                }
            }
            #pragma unroll
            for (int j = 0; j < 4; ++j) {            // FFN2 (own-wave H rows)
                int rowa = wid*64 + j*16 + llo;
                h8 ah = ldh(&S[KP + rowa*16 + swg(rowa, lhi)]);
                cf[j][0] = __builtin_amdgcn_mfma_f32_16x16x32_f16(ah, b20, cf[j][0], 0,0,0);
                cf[j][1] = __builtin_amdgcn_mfma_f32_16x16x32_f16(ah, b21, cf[j][1], 0,0,0);
            }
        }
        #pragma unroll
        for (int j = 0; j < 4; ++j) {                // FFN2 out -> KP (own-wave)
            int rowb = wid*64 + j*16 + lhi*4;
            #pragma unroll
            for (int rg = 0; rg < 4; ++rg) {
                int row = rowb + rg;
                S[KP + row*16 + swg(row, llo >> 2) + (llo & 3)] = pkh(cf[j][0][rg], cf[j][1][rg]);
            }
        }
        #pragma unroll
        for (int g = 0; g < 4; ++g) {                // residual (own row)
            uint4 v = *(const uint4*)&S[KP + tid*16 + ((g ^ myk) << 2)];
            X[4*g+0] += lo16(v.x); X[16+4*g+0] += hi16(v.x);
            X[4*g+1] += lo16(v.y); X[16+4*g+1] += hi16(v.y);
            X[4*g+2] += lo16(v.z); X[16+4*g+2] += hi16(v.z);
            X[4*g+3] += lo16(v.w); X[16+4*g+3] += hi16(v.w);
        }
    }

    // ---- final LN + weight-tied logits ----
    ln_write(X, &S[XN], tid);
    {
        h8 bt = ldh(ws + 12288 + llo*16 + boff);
        #pragma unroll
        for (int j = 0; j < 4; ++j) {
            int rowa = wid*64 + j*16 + llo;
            h8 a = ldh(&S[XN + rowa*16 + swg(rowa, lhi)]);
            f32x4 lg = __builtin_amdgcn_mfma_f32_16x16x32_f16(a, bt, zz, 0,0,0);
            int rowb = wid*64 + j*16 + lhi*4;
            #pragma unroll
            for (int rg = 0; rg < 4; ++rg) {
                int row = rowb + rg;
                S[KP + row*16 + swg(row, llo >> 2) + (llo & 3)] = __float_as_uint(lg[rg]);
            }
        }
    }
    __syncthreads();                                 // logits visible cross-wave
    #pragma unroll
    for (int i = 0; i < VOC; ++i) {                  // coalesced f32 out
        int flat = tid + ROWS * i;
        int row = flat / VOC, col = flat % VOC;
        out[gbase*VOC + flat] =
            __uint_as_float(S[KP + row*16 + (((col >> 2) ^ ((row >> 1) & 3)) << 2) + (col & 3)]);
    }
}

extern "C" void kernel_launch(void* const* d_in, const int* in_sizes, int n_in,
                              void* d_out, int out_size, void* d_ws, size_t ws_size,
                              hipStream_t stream) {
    const int*   toks = (const int*)  d_in[0];
    const float* temb = (const float*)d_in[1];
    const float* pemb = (const float*)d_in[2];
    const float* wq   = (const float*)d_in[3];
    const float* wk   = (const float*)d_in[4];
    const float* wv   = (const float*)d_in[5];
    const float* wo   = (const float*)d_in[6];
    const float* w1   = (const float*)d_in[7];
    const float* w2   = (const float*)d_in[8];
    unsigned int* ws  = (unsigned int*)d_ws;         // 12544 u32 = 50 KB used
    float* out = (float*)d_out;
    const int batch = in_sizes[0] / SEQ;             // 131072
    const int nblk  = (batch * SEQ) / ROWS;          // 2048

    prep<<<dim3(25), dim3(64), 0, stream>>>(temb, wq, wk, wv, wo, w1, w2, ws);
    tf_mfma<<<dim3(nblk), dim3(ROWS), 0, stream>>>(toks, temb, pemb, ws, out);
}